// Round 4
// baseline (102.872 us; speedup 1.0000x reference)
//
#include <hip/hip_runtime.h>

#define N 64
#define MARGIN 0.1f
#define WAVES_PER_BLOCK 4
#define NBLOCKS 2048

// closed form (verified R2..R14, absmax 0.0): row_loss = sum_e u_e*(q_e - p_e)
//   p_e = #{k: lab_k < lab_e},  u_e = sc_e - MARGIN*p_e,  q_e = #{k: u_k < u_e}
//
// R15: R11's proven 3-op compute (sub + ashr + add, 4 independent chains --
// both 2-op variants R13/R14 regressed; kernel is stall-bound, not
// issue-bound) + two structural fixes aimed at the stalls:
//   1) __launch_bounds__(256, 8): pin min 8 waves/SIMD -> VGPR <= 64.
//      Previous rounds left the allocator free to burn 128 VGPR (4
//      waves/SIMD), halving latency-hiding TLP. Grid is exactly 32
//      waves/CU, so occupancy is pure VGPR-bound.
//   2) software prefetch of the NEXT row's per-lane labv/scv BEFORE the
//      lgkm drain. The asm "memory" clobber pins loads in program order,
//      so without this each row pays a full serial HBM/L2 round trip.
//      The per-lane load touches exactly the lines pass1's float4
//      broadcasts re-read; the row base deliberately avoids
//      readfirstlane so those broadcasts stay on the VECTOR L1 path the
//      prefetch warms (scalar s_load uses a separate cache).

__global__ __launch_bounds__(256, 8) void mmrl_partial(const float* __restrict__ scores,
                                                       const float* __restrict__ labels,
                                                       float* __restrict__ partial,
                                                       int rows) {
    __shared__ float ubuf[WAVES_PER_BLOCK][N];
    __shared__ float wsum[WAVES_PER_BLOCK];

    const int lane = threadIdx.x & 63;
    const int w    = threadIdx.x >> 6;
    const int gwave = blockIdx.x * WAVES_PER_BLOCK + w;
    const int nwaves = NBLOCKS * WAVES_PER_BLOCK;

    float acc = 0.0f;

    // prologue: first row's per-lane copies
    float labv = 0.0f, scv = 0.0f;
    if (gwave < rows) {
        labv = labels[gwave * N + lane];
        scv  = scores[gwave * N + lane];
    }

    for (int row = gwave; row < rows; row += nwaves) {
        // ---- prefetch next row's per-lane copies (warms L1 for next pass1) ----
        const int next  = row + nwaves;
        const int pnext = (next < rows) ? next : row;   // clamp: harmless re-read
        const float labv_n = labels[pnext * N + lane];
        const float scv_n  = scores[pnext * N + lane];

        // ---- pass 1: label rank p (vector-L1 float4 broadcasts; sign-bit) ----
        const float4* L4 = (const float4*)(labels + row * N);
        int p0 = 0, p1 = 0, p2 = 0, p3 = 0;       // accumulate 0 / -1
        #pragma unroll
        for (int kk = 0; kk < N / 4; ++kk) {
            const float4 a = L4[kk];
            p0 += __float_as_int(a.x - labv) >> 31;
            p1 += __float_as_int(a.y - labv) >> 31;
            p2 += __float_as_int(a.z - labv) >> 31;
            p3 += __float_as_int(a.w - labv) >> 31;
        }
        const int pv = -((p0 + p1) + (p2 + p3));

        const float u = fmaf(-MARGIN, (float)pv, scv);

        // ---- pass 2: u rank q (LDS uniform float4 broadcasts; sign-bit) ----
        ubuf[w][lane] = u;
        asm volatile("s_waitcnt lgkmcnt(0)" ::: "memory");  // intra-wave LDS RAW
        const float4* U4 = (const float4*)ubuf[w];
        int q0 = 0, q1 = 0, q2 = 0, q3 = 0;
        #pragma unroll
        for (int kk = 0; kk < N / 4; ++kk) {
            const float4 b = U4[kk];
            q0 += __float_as_int(b.x - u) >> 31;
            q1 += __float_as_int(b.y - u) >> 31;
            q2 += __float_as_int(b.z - u) >> 31;
            q3 += __float_as_int(b.w - u) >> 31;
        }
        const int qv = -((q0 + q1) + (q2 + q3));

        acc = fmaf(u, (float)(qv - pv), acc);

        labv = labv_n;   // rotate prefetched copies into place
        scv  = scv_n;
    }

    // ---- wave reduction ----
    #pragma unroll
    for (int off = 32; off > 0; off >>= 1)
        acc += __shfl_down(acc, off, 64);

    if (lane == 0) wsum[w] = acc;
    __syncthreads();
    if (threadIdx.x == 0) {
        float s = 0.0f;
        #pragma unroll
        for (int i = 0; i < WAVES_PER_BLOCK; ++i) s += wsum[i];
        partial[blockIdx.x] = s;          // plain store, no atomic, no fence
    }
}

__global__ __launch_bounds__(256) void mmrl_reduce(const float* __restrict__ partial,
                                                   float* __restrict__ out,
                                                   int npartial, float inv_rows) {
    const int t = threadIdx.x;
    float s = 0.0f;
    for (int i = t; i < npartial; i += 256)
        s += partial[i];
    #pragma unroll
    for (int off = 32; off > 0; off >>= 1)
        s += __shfl_down(s, off, 64);
    __shared__ float wsum[4];
    if ((t & 63) == 0) wsum[t >> 6] = s;
    __syncthreads();
    if (t == 0)
        out[0] = (wsum[0] + wsum[1] + wsum[2] + wsum[3]) * inv_rows;
}

extern "C" void kernel_launch(void* const* d_in, const int* in_sizes, int n_in,
                              void* d_out, int out_size, void* d_ws, size_t ws_size,
                              hipStream_t stream) {
    const float* scores = (const float*)d_in[0];
    const float* labels = (const float*)d_in[1];
    float* out = (float*)d_out;
    float* partial = (float*)d_ws;        // 2048 floats = 8 KB << ws_size
    const int rows = in_sizes[0] / N;     // 32768

    mmrl_partial<<<NBLOCKS, 256, 0, stream>>>(scores, labels, partial, rows);
    mmrl_reduce<<<1, 256, 0, stream>>>(partial, out, NBLOCKS, 1.0f / (float)rows);
}

// Round 5
// 91.676 us; speedup vs baseline: 1.1221x; 1.1221x over previous
//
#include <hip/hip_runtime.h>

#define N 64
#define MARGIN 0.1f
#define WAVES_PER_BLOCK 4
#define NBLOCKS 2048

// closed form (verified R2..R15, absmax 0.0): row_loss = sum_e u_e*(q_e - p_e)
//   p_e = #{k: lab_k < lab_e},  u_e = sc_e - MARGIN*p_e,  q_e = #{k: u_k < u_e}
//
// R16: LDS-staged, double-buffered row pipeline.
//   R15 post-mortem: VGPR=32 forced the 16 in-flight float4 HBM broadcasts
//   into small batches -> serial exposed HBM latency (VALUBusy 29%, 57us).
//   Fix is structural: keep bulk row data in LDS, not registers.
//     - per row, only TWO per-lane global loads (labv_n, scv_n), issued at
//       the TOP of the iteration, ds-written / rotated at the BOTTOM ->
//       their HBM latency hides under both rank passes (T14 split).
//     - pass 1 broadcasts from LDS (uniform ds_read_b128, conflict-free,
//       ~120cy) instead of global: small register batches are now cheap,
//       so __launch_bounds__(256,8) (VGPR<=64, 8 waves/SIMD) is safe.
//     - per-lane labv stays in a register (no LDS read needed).
//   Compute: R11's proven sign-bit form, 4 independent chains
//   (both 2-op variants R13/R14 regressed; do not revisit).

__global__ __launch_bounds__(256, 8) void mmrl_partial(const float* __restrict__ scores,
                                                       const float* __restrict__ labels,
                                                       float* __restrict__ partial,
                                                       int rows) {
    __shared__ float lbuf[WAVES_PER_BLOCK][2][N];   // double-buffered label rows
    __shared__ float ubuf[WAVES_PER_BLOCK][N];
    __shared__ float wsum[WAVES_PER_BLOCK];

    const int lane = threadIdx.x & 63;
    const int w    = threadIdx.x >> 6;
    const int gwave = blockIdx.x * WAVES_PER_BLOCK + w;
    const int nwaves = NBLOCKS * WAVES_PER_BLOCK;

    float acc = 0.0f;

    if (gwave < rows) {   // wave-uniform (gwave is uniform within the wave)
        // ---- prologue: row0 per-lane copies; stage row0 labels into buf0 ----
        const int base0 = __builtin_amdgcn_readfirstlane(gwave) * N;
        float labv = labels[base0 + lane];
        float scv  = scores[base0 + lane];
        lbuf[w][0][lane] = labv;
        int b = 0;

        for (int row = gwave; row < rows; row += nwaves) {
            // ---- early: issue next row's per-lane loads (consumed at bottom;
            //      ~full iteration of slack hides HBM latency) ----
            const int next  = row + nwaves;
            const int nbase = __builtin_amdgcn_readfirstlane(next < rows ? next : row) * N;
            const float labv_n = labels[nbase + lane];
            const float scv_n  = scores[nbase + lane];

            // ---- pass 1: label rank p from LDS broadcasts (uniform b128) ----
            asm volatile("s_waitcnt lgkmcnt(0)" ::: "memory");  // lbuf[w][b] ready
            const float4* L4 = (const float4*)lbuf[w][b];
            int p0 = 0, p1 = 0, p2 = 0, p3 = 0;       // accumulate 0 / -1
            #pragma unroll
            for (int kk = 0; kk < N / 4; ++kk) {
                const float4 a = L4[kk];
                p0 += __float_as_int(a.x - labv) >> 31;
                p1 += __float_as_int(a.y - labv) >> 31;
                p2 += __float_as_int(a.z - labv) >> 31;
                p3 += __float_as_int(a.w - labv) >> 31;
            }
            const int pv = -((p0 + p1) + (p2 + p3));

            const float u = fmaf(-MARGIN, (float)pv, scv);

            // ---- pass 2: u rank q (LDS uniform b128 broadcasts) ----
            ubuf[w][lane] = u;
            asm volatile("s_waitcnt lgkmcnt(0)" ::: "memory");  // intra-wave RAW
            const float4* U4 = (const float4*)ubuf[w];
            int q0 = 0, q1 = 0, q2 = 0, q3 = 0;
            #pragma unroll
            for (int kk = 0; kk < N / 4; ++kk) {
                const float4 c = U4[kk];
                q0 += __float_as_int(c.x - u) >> 31;
                q1 += __float_as_int(c.y - u) >> 31;
                q2 += __float_as_int(c.z - u) >> 31;
                q3 += __float_as_int(c.w - u) >> 31;
            }
            const int qv = -((q0 + q1) + (q2 + q3));

            acc = fmaf(u, (float)(qv - pv), acc);

            // ---- late: rotate; stage next labels into the other buffer.
            //      The vmcnt wait for labv_n lands HERE (latency already
            //      covered by both passes above). ----
            lbuf[w][b ^ 1][lane] = labv_n;
            labv = labv_n;
            scv  = scv_n;
            b ^= 1;
        }
    }

    // ---- wave reduction ----
    #pragma unroll
    for (int off = 32; off > 0; off >>= 1)
        acc += __shfl_down(acc, off, 64);

    if (lane == 0) wsum[w] = acc;
    __syncthreads();
    if (threadIdx.x == 0) {
        float s = 0.0f;
        #pragma unroll
        for (int i = 0; i < WAVES_PER_BLOCK; ++i) s += wsum[i];
        partial[blockIdx.x] = s;          // plain store, no atomic, no fence
    }
}

__global__ __launch_bounds__(256) void mmrl_reduce(const float* __restrict__ partial,
                                                   float* __restrict__ out,
                                                   int npartial, float inv_rows) {
    const int t = threadIdx.x;
    float s = 0.0f;
    for (int i = t; i < npartial; i += 256)
        s += partial[i];
    #pragma unroll
    for (int off = 32; off > 0; off >>= 1)
        s += __shfl_down(s, off, 64);
    __shared__ float wsum[4];
    if ((t & 63) == 0) wsum[t >> 6] = s;
    __syncthreads();
    if (t == 0)
        out[0] = (wsum[0] + wsum[1] + wsum[2] + wsum[3]) * inv_rows;
}

extern "C" void kernel_launch(void* const* d_in, const int* in_sizes, int n_in,
                              void* d_out, int out_size, void* d_ws, size_t ws_size,
                              hipStream_t stream) {
    const float* scores = (const float*)d_in[0];
    const float* labels = (const float*)d_in[1];
    float* out = (float*)d_out;
    float* partial = (float*)d_ws;        // 2048 floats = 8 KB << ws_size
    const int rows = in_sizes[0] / N;     // 32768

    mmrl_partial<<<NBLOCKS, 256, 0, stream>>>(scores, labels, partial, rows);
    mmrl_reduce<<<1, 256, 0, stream>>>(partial, out, NBLOCKS, 1.0f / (float)rows);
}